// Round 1
// baseline (310.428 us; speedup 1.0000x reference)
//
#include <hip/hip_runtime.h>
#include <hip/hip_bf16.h>

// Problem: N=64, T=2048, D=256, fp32.
// out = [context (N*D)] ++ [norm_attention (N*T)]
// Key insight: softmax-then-mask-then-renormalize == softmax restricted to
// t < lens[n]; attention is exactly 0 for t >= lens[n]. So key/value rows
// beyond lens[n] are never read.

#define N_B 64
#define T_S 2048
#define D_S 256
#define CHUNK 128
#define TPB 256

// Kernel 1: e[n,t] = <key[n,t,:], query[n,:]> for t < lens[n].
// One wave per t-row: 64 lanes x float4 = 256 floats, butterfly-reduce.
__global__ __launch_bounds__(TPB) void energy_kernel(
    const float* __restrict__ q, const float* __restrict__ k,
    const int* __restrict__ lens, float* __restrict__ e) {
  const int n = blockIdx.y;
  const int c = blockIdx.x;
  const int L = lens[n];
  const int t0 = c * CHUNK;
  if (t0 >= L) return;
  const int tend = min(t0 + CHUNK, L);
  const int lane = threadIdx.x & 63;
  const int wave = threadIdx.x >> 6;

  const float4 qv =
      reinterpret_cast<const float4*>(q + (size_t)n * D_S)[lane];
  const float* kbase = k + (size_t)n * T_S * D_S;

  for (int t = t0 + wave; t < tend; t += 4) {
    const float4 kv =
        reinterpret_cast<const float4*>(kbase + (size_t)t * D_S)[lane];
    float s = qv.x * kv.x + qv.y * kv.y + qv.z * kv.z + qv.w * kv.w;
#pragma unroll
    for (int off = 32; off > 0; off >>= 1) s += __shfl_xor(s, off, 64);
    if (lane == 0) e[(size_t)n * T_S + t] = s;
  }
}

// Kernel 2: per (n, chunk): reduce m,Z over valid energies (cheap, L2-hot),
// write attention slice (0 past lens), accumulate context partial.
__global__ __launch_bounds__(TPB) void softmax_ctx_kernel(
    const float* __restrict__ v, const int* __restrict__ lens,
    const float* __restrict__ e, float* __restrict__ out_ctx,
    float* __restrict__ out_attn) {
  const int n = blockIdx.y;
  const int c = blockIdx.x;
  const int L = lens[n];
  const int t0 = c * CHUNK;
  const int tid = threadIdx.x;

  __shared__ float red[4];
  __shared__ float a_sh[CHUNK];
  __shared__ float mz[2];

  const float* erow = e + (size_t)n * T_S;

  // --- max over valid t ---
  float m = -1e30f;
  for (int t = tid; t < L; t += TPB) m = fmaxf(m, erow[t]);
#pragma unroll
  for (int off = 32; off > 0; off >>= 1) m = fmaxf(m, __shfl_xor(m, off, 64));
  if ((tid & 63) == 0) red[tid >> 6] = m;
  __syncthreads();
  if (tid == 0)
    mz[0] = fmaxf(fmaxf(red[0], red[1]), fmaxf(red[2], red[3]));
  __syncthreads();
  m = mz[0];

  // --- sum of exp over valid t ---
  float z = 0.f;
  for (int t = tid; t < L; t += TPB) z += __expf(erow[t] - m);
#pragma unroll
  for (int off = 32; off > 0; off >>= 1) z += __shfl_xor(z, off, 64);
  if ((tid & 63) == 0) red[tid >> 6] = z;
  __syncthreads();
  if (tid == 0) mz[1] = red[0] + red[1] + red[2] + red[3];
  __syncthreads();
  const float invZ = 1.0f / mz[1];

  // --- attention slice for this chunk (includes zeros past lens) ---
  if (tid < CHUNK) {
    const int t = t0 + tid;
    const float a = (t < L) ? __expf(erow[t] - m) * invZ : 0.f;
    out_attn[(size_t)n * T_S + t] = a;
    a_sh[tid] = a;
  }
  __syncthreads();

  // --- context partial: thread d accumulates over this chunk's valid t ---
  if (t0 < L) {
    const int tend = min(t0 + CHUNK, L);
    const float* vbase = v + (size_t)n * T_S * D_S;
    float acc = 0.f;
    for (int t = t0; t < tend; ++t)
      acc = fmaf(a_sh[t - t0], vbase[(size_t)t * D_S + tid], acc);
    atomicAdd(&out_ctx[(size_t)n * D_S + tid], acc);
  }
}

extern "C" void kernel_launch(void* const* d_in, const int* in_sizes, int n_in,
                              void* d_out, int out_size, void* d_ws,
                              size_t ws_size, hipStream_t stream) {
  const float* query = (const float*)d_in[0];
  const float* key = (const float*)d_in[1];
  const float* value = (const float*)d_in[2];
  const int* lens = (const int*)d_in[3];

  float* out_ctx = (float*)d_out;                 // N*D floats
  float* out_attn = (float*)d_out + N_B * D_S;    // N*T floats
  float* e = (float*)d_ws;                        // N*T floats (512 KB)

  dim3 grid(T_S / CHUNK, N_B);  // (16, 64)

  energy_kernel<<<grid, TPB, 0, stream>>>(query, key, lens, e);

  // context region is poisoned 0xAA each call; atomics need zeros.
  hipMemsetAsync(out_ctx, 0, (size_t)N_B * D_S * sizeof(float), stream);

  softmax_ctx_kernel<<<grid, TPB, 0, stream>>>(value, lens, e, out_ctx,
                                               out_attn);
}

// Round 2
// 266.907 us; speedup vs baseline: 1.1631x; 1.1631x over previous
//
#include <hip/hip_runtime.h>

// N=64, T=2048, D=256, fp32. out = [context (N*D)] ++ [norm_attention (N*T)].
// softmax+mask+renorm == softmax over t < lens[n]; attention exactly 0 past lens.
// 3 kernels: energy (valid rows only) -> per-row stats (m, 1/Z) -> attn+context.

#define N_B 64
#define T_S 2048
#define D_S 256
#define TPB 256
#define RC 64  // rows (t) per block in energy/ctx kernels -> grid (32, 64)

// ---- Kernel 1: e[n,t] = <key[n,t,:], query[n,:]> for t < lens[n] ----
// One wave per row, 64 lanes x float4 = 256 floats; 2 rows in flight.
__global__ __launch_bounds__(TPB) void energy_kernel(
    const float* __restrict__ q, const float* __restrict__ k,
    const int* __restrict__ lens, float* __restrict__ e) {
  const int n = blockIdx.y;
  const int L = lens[n];
  const int t0 = blockIdx.x * RC;
  if (t0 >= L) return;
  const int tend = min(t0 + RC, L);
  const int lane = threadIdx.x & 63;
  const int wave = threadIdx.x >> 6;

  const float4 qv = reinterpret_cast<const float4*>(q + (size_t)n * D_S)[lane];
  const float* kbase = k + (size_t)n * T_S * D_S;
  float* erow = e + (size_t)n * T_S;

  int t = t0 + wave;
  for (; t + 4 < tend; t += 8) {
    const float4 a =
        reinterpret_cast<const float4*>(kbase + (size_t)t * D_S)[lane];
    const float4 b =
        reinterpret_cast<const float4*>(kbase + (size_t)(t + 4) * D_S)[lane];
    float s0 = a.x * qv.x + a.y * qv.y + a.z * qv.z + a.w * qv.w;
    float s1 = b.x * qv.x + b.y * qv.y + b.z * qv.z + b.w * qv.w;
#pragma unroll
    for (int off = 32; off > 0; off >>= 1) {
      s0 += __shfl_xor(s0, off, 64);
      s1 += __shfl_xor(s1, off, 64);
    }
    if (lane == 0) {
      erow[t] = s0;
      erow[t + 4] = s1;
    }
  }
  if (t < tend) {
    const float4 a =
        reinterpret_cast<const float4*>(kbase + (size_t)t * D_S)[lane];
    float s0 = a.x * qv.x + a.y * qv.y + a.z * qv.z + a.w * qv.w;
#pragma unroll
    for (int off = 32; off > 0; off >>= 1) s0 += __shfl_xor(s0, off, 64);
    if (lane == 0) erow[t] = s0;
  }
}

// ---- Kernel 2: per-row (m, 1/Z) over valid energies; 64 blocks ----
__global__ __launch_bounds__(TPB) void stats_kernel(
    const int* __restrict__ lens, const float* __restrict__ e,
    float2* __restrict__ mz) {
  const int n = blockIdx.x;
  const int L = lens[n];
  const float* erow = e + (size_t)n * T_S;
  const int tid = threadIdx.x;
  __shared__ float red[4];

  float m = -1e30f;
  for (int t = tid; t < L; t += TPB) m = fmaxf(m, erow[t]);
#pragma unroll
  for (int off = 32; off > 0; off >>= 1) m = fmaxf(m, __shfl_xor(m, off, 64));
  if ((tid & 63) == 0) red[tid >> 6] = m;
  __syncthreads();
  m = fmaxf(fmaxf(red[0], red[1]), fmaxf(red[2], red[3]));
  __syncthreads();

  float z = 0.f;
  for (int t = tid; t < L; t += TPB) z += __expf(erow[t] - m);
#pragma unroll
  for (int off = 32; off > 0; off >>= 1) z += __shfl_xor(z, off, 64);
  if ((tid & 63) == 0) red[tid >> 6] = z;
  __syncthreads();
  if (tid == 0) {
    const float Z = red[0] + red[1] + red[2] + red[3];
    mz[n] = make_float2(m, 1.0f / Z);
  }
}

// ---- Kernel 3: attention slice + context partial ----
// Block = (n, 64-row chunk). 256 thr = 64 d-groups (float4) x 4 t-groups.
__global__ __launch_bounds__(TPB) void ctx_kernel(
    const float* __restrict__ v, const int* __restrict__ lens,
    const float* __restrict__ e, const float2* __restrict__ mz,
    float* __restrict__ out_ctx, float* __restrict__ out_attn) {
  const int n = blockIdx.y;
  const int L = lens[n];
  const int t0 = blockIdx.x * RC;
  const int tid = threadIdx.x;

  __shared__ float a_sh[RC];
  __shared__ float4 part[TPB];

  const float2 s = mz[n];
  if (tid < RC) {
    const int t = t0 + tid;
    const float a = (t < L) ? __expf(e[(size_t)n * T_S + t] - s.x) * s.y : 0.f;
    out_attn[(size_t)n * T_S + t] = a;
    a_sh[tid] = a;
  }
  __syncthreads();
  if (t0 >= L) return;

  const int nv = min(RC, L - t0);
  const int dg = tid & 63;  // d = dg*4
  const int tg = tid >> 6;  // 4 t-groups
  const float* vbase = v + (size_t)n * T_S * D_S + (size_t)t0 * D_S;

  float4 acc0 = {0.f, 0.f, 0.f, 0.f}, acc1 = {0.f, 0.f, 0.f, 0.f};
  int j = tg;
  for (; j + 4 < nv; j += 8) {
    const float4 v0 =
        reinterpret_cast<const float4*>(vbase + (size_t)j * D_S)[dg];
    const float4 v1 =
        reinterpret_cast<const float4*>(vbase + (size_t)(j + 4) * D_S)[dg];
    const float a0 = a_sh[j], a1 = a_sh[j + 4];
    acc0.x = fmaf(a0, v0.x, acc0.x);
    acc0.y = fmaf(a0, v0.y, acc0.y);
    acc0.z = fmaf(a0, v0.z, acc0.z);
    acc0.w = fmaf(a0, v0.w, acc0.w);
    acc1.x = fmaf(a1, v1.x, acc1.x);
    acc1.y = fmaf(a1, v1.y, acc1.y);
    acc1.z = fmaf(a1, v1.z, acc1.z);
    acc1.w = fmaf(a1, v1.w, acc1.w);
  }
  if (j < nv) {
    const float4 v0 =
        reinterpret_cast<const float4*>(vbase + (size_t)j * D_S)[dg];
    const float a0 = a_sh[j];
    acc0.x = fmaf(a0, v0.x, acc0.x);
    acc0.y = fmaf(a0, v0.y, acc0.y);
    acc0.z = fmaf(a0, v0.z, acc0.z);
    acc0.w = fmaf(a0, v0.w, acc0.w);
  }
  acc0.x += acc1.x;
  acc0.y += acc1.y;
  acc0.z += acc1.z;
  acc0.w += acc1.w;

  part[tid] = acc0;
  __syncthreads();
  if (tg == 0) {
    float4 r = part[dg];
    const float4 r1 = part[dg + 64], r2 = part[dg + 128], r3 = part[dg + 192];
    r.x += r1.x + r2.x + r3.x;
    r.y += r1.y + r2.y + r3.y;
    r.z += r1.z + r2.z + r3.z;
    r.w += r1.w + r2.w + r3.w;
    float* dst = out_ctx + (size_t)n * D_S + dg * 4;
    atomicAdd(dst + 0, r.x);
    atomicAdd(dst + 1, r.y);
    atomicAdd(dst + 2, r.z);
    atomicAdd(dst + 3, r.w);
  }
}

extern "C" void kernel_launch(void* const* d_in, const int* in_sizes, int n_in,
                              void* d_out, int out_size, void* d_ws,
                              size_t ws_size, hipStream_t stream) {
  const float* query = (const float*)d_in[0];
  const float* key = (const float*)d_in[1];
  const float* value = (const float*)d_in[2];
  const int* lens = (const int*)d_in[3];

  float* out_ctx = (float*)d_out;               // N*D floats
  float* out_attn = (float*)d_out + N_B * D_S;  // N*T floats
  float* e = (float*)d_ws;                      // N*T floats (512 KB)
  float2* mz = (float2*)((float*)d_ws + (size_t)N_B * T_S);  // 64 float2

  const dim3 grid(T_S / RC, N_B);  // (32, 64)

  // out_ctx is poisoned 0xAA each call; atomics need zeros.
  hipMemsetAsync(out_ctx, 0, (size_t)N_B * D_S * sizeof(float), stream);

  energy_kernel<<<grid, TPB, 0, stream>>>(query, key, lens, e);
  stats_kernel<<<N_B, TPB, 0, stream>>>(lens, e, mz);
  ctx_kernel<<<grid, TPB, 0, stream>>>(value, lens, e, mz, out_ctx, out_attn);
}

// Round 3
// 260.232 us; speedup vs baseline: 1.1929x; 1.0256x over previous
//
#include <hip/hip_runtime.h>

// N=64, T=2048, D=256, fp32. out = [context (N*D)] ++ [norm_attention (N*T)].
// softmax+mask+renorm == softmax restricted to t < lens[n]; attn == 0 past lens.
//
// Split-softmax, 2 kernels, no atomics/memset:
//  K1 (n, chunk of 64 t): e = K·q (wave butterfly), chunk max m_c & Z_c,
//     p = exp(e - m_c) -> ws, partial context O_c = p·V -> ws.
//  K2 (per n): merge (m_c, Z_c) -> scale s_c = exp(m_c - m)/Z;
//     attn[t] = p[t]*s_c(t) (0 past lens); context[d] = sum_c s_c * O_c[d].

#define N_B 64
#define T_S 2048
#define D_S 256
#define TPB 256
#define RC 64          // t-rows per chunk
#define NC (T_S / RC)  // 32 chunks per row

__global__ __launch_bounds__(TPB) void fused_kernel(
    const float* __restrict__ q, const float* __restrict__ k,
    const float* __restrict__ v, const int* __restrict__ lens,
    float* __restrict__ p_out, float2* __restrict__ mzc,
    float* __restrict__ Oc) {
  const int n = blockIdx.y;
  const int c = blockIdx.x;
  const int L = lens[n];
  const int t0 = c * RC;
  if (t0 >= L) return;
  const int tend = min(t0 + RC, L);
  const int tid = threadIdx.x;
  const int lane = tid & 63;
  const int wave = tid >> 6;

  __shared__ float e_sh[RC];
  __shared__ float p_sh[RC];
  __shared__ float4 part[TPB];

  if (tid < RC) e_sh[tid] = -1e30f;
  __syncthreads();

  // ---- phase 1: energies for valid rows (one wave per row, 2 in flight) ----
  const float4 qv = reinterpret_cast<const float4*>(q + (size_t)n * D_S)[lane];
  const float* kbase = k + (size_t)n * T_S * D_S;
  int t = t0 + wave;
  for (; t + 4 < tend; t += 8) {
    const float4 a =
        reinterpret_cast<const float4*>(kbase + (size_t)t * D_S)[lane];
    const float4 b =
        reinterpret_cast<const float4*>(kbase + (size_t)(t + 4) * D_S)[lane];
    float s0 = a.x * qv.x + a.y * qv.y + a.z * qv.z + a.w * qv.w;
    float s1 = b.x * qv.x + b.y * qv.y + b.z * qv.z + b.w * qv.w;
#pragma unroll
    for (int off = 32; off > 0; off >>= 1) {
      s0 += __shfl_xor(s0, off, 64);
      s1 += __shfl_xor(s1, off, 64);
    }
    if (lane == 0) {
      e_sh[t - t0] = s0;
      e_sh[t + 4 - t0] = s1;
    }
  }
  if (t < tend) {
    const float4 a =
        reinterpret_cast<const float4*>(kbase + (size_t)t * D_S)[lane];
    float s0 = a.x * qv.x + a.y * qv.y + a.z * qv.z + a.w * qv.w;
#pragma unroll
    for (int off = 32; off > 0; off >>= 1) s0 += __shfl_xor(s0, off, 64);
    if (lane == 0) e_sh[t - t0] = s0;
  }
  __syncthreads();

  // ---- phase 2: chunk-local softmax partials (wave 0; invalid rows -> p=0) --
  if (wave == 0) {
    const float e = e_sh[lane];
    float m = e;
#pragma unroll
    for (int off = 32; off > 0; off >>= 1) m = fmaxf(m, __shfl_xor(m, off, 64));
    const float pv = __expf(e - m);  // e=-1e30 -> 0
    float z = pv;
#pragma unroll
    for (int off = 32; off > 0; off >>= 1) z += __shfl_xor(z, off, 64);
    p_sh[lane] = pv;
    p_out[(size_t)n * T_S + t0 + lane] = pv;
    if (lane == 0) mzc[n * NC + c] = make_float2(m, z);
  }
  __syncthreads();

  // ---- phase 3: partial context O_c = sum_t p_t * v_t ----
  const int dg = tid & 63;  // d = dg*4
  const int tg = tid >> 6;  // 4 t-groups
  const int nv = tend - t0;
  const float* vbase = v + (size_t)n * T_S * D_S + (size_t)t0 * D_S;

  float4 acc0 = {0.f, 0.f, 0.f, 0.f}, acc1 = {0.f, 0.f, 0.f, 0.f};
  int j = tg;
  for (; j + 4 < nv; j += 8) {
    const float4 v0 =
        reinterpret_cast<const float4*>(vbase + (size_t)j * D_S)[dg];
    const float4 v1 =
        reinterpret_cast<const float4*>(vbase + (size_t)(j + 4) * D_S)[dg];
    const float a0 = p_sh[j], a1 = p_sh[j + 4];
    acc0.x = fmaf(a0, v0.x, acc0.x);
    acc0.y = fmaf(a0, v0.y, acc0.y);
    acc0.z = fmaf(a0, v0.z, acc0.z);
    acc0.w = fmaf(a0, v0.w, acc0.w);
    acc1.x = fmaf(a1, v1.x, acc1.x);
    acc1.y = fmaf(a1, v1.y, acc1.y);
    acc1.z = fmaf(a1, v1.z, acc1.z);
    acc1.w = fmaf(a1, v1.w, acc1.w);
  }
  if (j < nv) {
    const float4 v0 =
        reinterpret_cast<const float4*>(vbase + (size_t)j * D_S)[dg];
    const float a0 = p_sh[j];
    acc0.x = fmaf(a0, v0.x, acc0.x);
    acc0.y = fmaf(a0, v0.y, acc0.y);
    acc0.z = fmaf(a0, v0.z, acc0.z);
    acc0.w = fmaf(a0, v0.w, acc0.w);
  }
  acc0.x += acc1.x;
  acc0.y += acc1.y;
  acc0.z += acc1.z;
  acc0.w += acc1.w;

  part[tid] = acc0;
  __syncthreads();
  if (tg == 0) {
    float4 r = part[dg];
    const float4 r1 = part[dg + 64], r2 = part[dg + 128], r3 = part[dg + 192];
    r.x += r1.x + r2.x + r3.x;
    r.y += r1.y + r2.y + r3.y;
    r.z += r1.z + r2.z + r3.z;
    r.w += r1.w + r2.w + r3.w;
    reinterpret_cast<float4*>(Oc + ((size_t)(n * NC + c)) * D_S)[dg] = r;
  }
}

__global__ __launch_bounds__(TPB) void merge_kernel(
    const int* __restrict__ lens, const float* __restrict__ p_in,
    const float2* __restrict__ mzc, const float* __restrict__ Oc,
    float* __restrict__ out_ctx, float* __restrict__ out_attn) {
  const int n = blockIdx.x;
  const int L = lens[n];
  const int nc = (L + RC - 1) / RC;
  const int tid = threadIdx.x;
  __shared__ float s_sh[NC];

  if (tid < 64) {
    float m = -1e30f, z = 0.f;
    if (tid < nc) {
      const float2 mz = mzc[n * NC + tid];
      m = mz.x;
      z = mz.y;
    }
    float M = m;
#pragma unroll
    for (int off = 32; off > 0; off >>= 1) M = fmaxf(M, __shfl_xor(M, off, 64));
    const float sc = __expf(m - M);  // 0 for invalid chunks
    float zs = z * sc;
#pragma unroll
    for (int off = 32; off > 0; off >>= 1) zs += __shfl_xor(zs, off, 64);
    if (tid < NC) s_sh[tid] = sc / zs;
  }
  __syncthreads();

  // attention (zeros past lens)
#pragma unroll
  for (int i = 0; i < T_S / TPB; ++i) {
    const int t = i * TPB + tid;
    const float a = (t < L) ? p_in[(size_t)n * T_S + t] * s_sh[t >> 6] : 0.f;
    out_attn[(size_t)n * T_S + t] = a;
  }

  // context: thread = d; sum over chunks (s_sh==0 kills invalid chunks)
  float acc = 0.f;
  const float* ob = Oc + (size_t)n * NC * D_S + tid;
#pragma unroll
  for (int c2 = 0; c2 < NC; ++c2) acc = fmaf(s_sh[c2], ob[c2 * D_S], acc);
  out_ctx[(size_t)n * D_S + tid] = acc;
}

extern "C" void kernel_launch(void* const* d_in, const int* in_sizes, int n_in,
                              void* d_out, int out_size, void* d_ws,
                              size_t ws_size, hipStream_t stream) {
  const float* query = (const float*)d_in[0];
  const float* key = (const float*)d_in[1];
  const float* value = (const float*)d_in[2];
  const int* lens = (const int*)d_in[3];

  float* out_ctx = (float*)d_out;               // N*D
  float* out_attn = (float*)d_out + N_B * D_S;  // N*T

  float* p = (float*)d_ws;                                   // N*T  (512 KB)
  float2* mzc = (float2*)(p + (size_t)N_B * T_S);            // N*NC (16 KB)
  float* Oc = (float*)(mzc + N_B * NC);                      // N*NC*D (2 MB)

  const dim3 grid(NC, N_B);  // (32, 64)
  fused_kernel<<<grid, TPB, 0, stream>>>(query, key, value, lens, p, mzc, Oc);
  merge_kernel<<<N_B, TPB, 0, stream>>>(lens, p, mzc, Oc, out_ctx, out_attn);
}

// Round 4
// 241.787 us; speedup vs baseline: 1.2839x; 1.0763x over previous
//
#include <hip/hip_runtime.h>

// N=64, T=2048, D=256, fp32. out = [context (N*D)] ++ [norm_attention (N*T)].
// softmax+mask+renorm == softmax restricted to t < lens[n]; attn == 0 past lens.
// Split-softmax, 2 kernels, no atomics/memset:
//  K1 (n, 64-t chunk): e = K·q (4 rows/wave-pass, 16-lane reduce), chunk (m,Z),
//     p = exp(e-m) -> ws, partial context O_c = p·V -> ws. K/V nontemporal.
//  K2 (n, quarter): merge chunk stats -> s_c = exp(m_c-m)/Z; attn = p*s_c
//     (0 past lens); context = sum_c s_c * O_c.

#define N_B 64
#define T_S 2048
#define D_S 256
#define TPB 256
#define RC 64
#define NC (T_S / RC)  // 32

typedef __attribute__((ext_vector_type(4))) float f4;
typedef __attribute__((ext_vector_type(2))) float f2;

__device__ __forceinline__ f4 ntload4(const float* p) {
  return __builtin_nontemporal_load((const f4*)p);
}
__device__ __forceinline__ f4 fma4(float s, f4 a, f4 b) {
  b.x = fmaf(s, a.x, b.x);
  b.y = fmaf(s, a.y, b.y);
  b.z = fmaf(s, a.z, b.z);
  b.w = fmaf(s, a.w, b.w);
  return b;
}

__global__ __launch_bounds__(TPB) void fused_kernel(
    const float* __restrict__ q, const float* __restrict__ k,
    const float* __restrict__ v, const int* __restrict__ lens,
    float* __restrict__ p_out, float2* __restrict__ mzc,
    float* __restrict__ Oc) {
  const int n = blockIdx.y, c = blockIdx.x;
  const int L = lens[n];
  const int t0 = c * RC;
  if (t0 >= L) return;
  const int tend = min(t0 + RC, L);
  const int tid = threadIdx.x;
  const int lane = tid & 63, wave = tid >> 6;

  __shared__ f4 q_sh[64];
  __shared__ float e_sh[RC];
  __shared__ float p_sh[RC];
  __shared__ f4 part[TPB];

  if (tid < 64) q_sh[tid] = ((const f4*)(q + (size_t)n * D_S))[tid];
  if (tid < RC) e_sh[tid] = -1e30f;
  __syncthreads();

  // ---- phase 1: energies. Wave owns 16 rows; 4 rows per pass, lane =
  // (quarter qd -> row, sublane s -> d-quarter). 16 independent loads/wave.
  {
    const int s = lane & 15, qd = lane >> 4;
    const float* kb = k + (size_t)n * T_S * D_S + s * 4;
    const int rbase = t0 + wave * 16 + qd;
#pragma unroll
    for (int g = 0; g < 4; ++g) {
      const int r = rbase + g * 4;  // always < T_S: loads in-bounds
      const float* krow = kb + (size_t)r * D_S;
      float acc = 0.f;
#pragma unroll
      for (int i = 0; i < 4; ++i) {
        const f4 kv = ntload4(krow + i * 64);
        const f4 qv = q_sh[i * 16 + s];
        acc = fmaf(kv.x, qv.x, acc);
        acc = fmaf(kv.y, qv.y, acc);
        acc = fmaf(kv.z, qv.z, acc);
        acc = fmaf(kv.w, qv.w, acc);
      }
#pragma unroll
      for (int off = 8; off > 0; off >>= 1) acc += __shfl_xor(acc, off, 64);
      if (s == 0 && r < tend) e_sh[r - t0] = acc;
    }
  }
  __syncthreads();

  // ---- phase 2: chunk-local softmax partials (invalid rows e=-1e30 -> p=0)
  if (wave == 0) {
    const float e = e_sh[lane];
    float m = e;
#pragma unroll
    for (int off = 32; off > 0; off >>= 1) m = fmaxf(m, __shfl_xor(m, off, 64));
    const float pv = __expf(e - m);
    float z = pv;
#pragma unroll
    for (int off = 32; off > 0; off >>= 1) z += __shfl_xor(z, off, 64);
    p_sh[lane] = pv;
    p_out[(size_t)n * T_S + t0 + lane] = pv;
    if (lane == 0) mzc[n * NC + c] = make_float2(m, z);
  }
  __syncthreads();

  // ---- phase 3: O_c = sum_t p_t * v_t. Fixed 16-iter fully-unrolled loop,
  // p=0 kills rows past tend (loads stay in-bounds: r < T_S).
  const int dg = tid & 63, tg = tid >> 6;
  const float* vb = v + (size_t)n * T_S * D_S + (size_t)t0 * D_S + dg * 4;
  f4 a0 = {0.f, 0.f, 0.f, 0.f}, a1 = a0, a2 = a0, a3 = a0;
#pragma unroll
  for (int j = 0; j < 4; ++j) {
    const int r0 = j * 16 + tg;
    const f4 v0 = ntload4(vb + (size_t)r0 * D_S);
    const f4 v1 = ntload4(vb + (size_t)(r0 + 4) * D_S);
    const f4 v2 = ntload4(vb + (size_t)(r0 + 8) * D_S);
    const f4 v3 = ntload4(vb + (size_t)(r0 + 12) * D_S);
    a0 = fma4(p_sh[r0], v0, a0);
    a1 = fma4(p_sh[r0 + 4], v1, a1);
    a2 = fma4(p_sh[r0 + 8], v2, a2);
    a3 = fma4(p_sh[r0 + 12], v3, a3);
  }
  part[tid] = (a0 + a1) + (a2 + a3);
  __syncthreads();
  if (tg == 0) {
    const f4 r = part[dg] + part[dg + 64] + part[dg + 128] + part[dg + 192];
    ((f4*)(Oc + ((size_t)(n * NC + c)) * D_S))[dg] = r;
  }
}

// ---- merge: grid (4, N). Block (cx,n): attn t-slice [cx*512, cx*512+512),
// ctx d-slice [cx*64, cx*64+64). Chunk-stats recomputed per block (L2-hot).
__global__ __launch_bounds__(TPB) void merge_kernel(
    const int* __restrict__ lens, const float* __restrict__ p_in,
    const float2* __restrict__ mzc, const float* __restrict__ Oc,
    float* __restrict__ out_ctx, float* __restrict__ out_attn) {
  const int n = blockIdx.y, cx = blockIdx.x;
  const int L = lens[n];
  const int nc = (L + RC - 1) / RC;
  const int tid = threadIdx.x;
  __shared__ float s_sh[NC];
  __shared__ float cpart[TPB];

  if (tid < 64) {
    float m = -1e30f, z = 0.f;
    if (tid < nc) {
      const float2 mz = mzc[n * NC + tid];
      m = mz.x;
      z = mz.y;
    }
    float M = m;
#pragma unroll
    for (int off = 32; off > 0; off >>= 1) M = fmaxf(M, __shfl_xor(M, off, 64));
    const float sc = __expf(m - M);  // 0 for invalid chunks
    float zs = z * sc;
#pragma unroll
    for (int off = 32; off > 0; off >>= 1) zs += __shfl_xor(zs, off, 64);
    if (tid < NC) s_sh[tid] = sc / zs;
  }
  __syncthreads();

  // attention slice (float2 per thread; zeros past lens)
  {
    const int t = cx * (T_S / 4) + tid * 2;
    const f2 p = *(const f2*)(p_in + (size_t)n * T_S + t);
    const float sc = s_sh[t >> 6];
    f2 a;
    a.x = (t < L) ? p.x * sc : 0.f;
    a.y = (t + 1 < L) ? p.y * sc : 0.f;
    *(f2*)(out_attn + (size_t)n * T_S + t) = a;
  }

  // context slice: thread (d = cx*64 + (tid&63), chunk-group tid>>6 of 8)
  {
    const int d = cx * 64 + (tid & 63);
    const int cg = tid >> 6;
    const float* ob = Oc + (size_t)n * NC * D_S + d;
    float acc = 0.f;
#pragma unroll
    for (int kk = 0; kk < 8; ++kk) {
      const int cc = cg + kk * 4;
      acc = fmaf(s_sh[cc], ob[(size_t)cc * D_S], acc);  // s==0 kills invalid
    }
    cpart[tid] = acc;
    __syncthreads();
    if (tid < 64)
      out_ctx[(size_t)n * D_S + d] =
          (cpart[tid] + cpart[tid + 64]) + (cpart[tid + 128] + cpart[tid + 192]);
  }
}

extern "C" void kernel_launch(void* const* d_in, const int* in_sizes, int n_in,
                              void* d_out, int out_size, void* d_ws,
                              size_t ws_size, hipStream_t stream) {
  const float* query = (const float*)d_in[0];
  const float* key = (const float*)d_in[1];
  const float* value = (const float*)d_in[2];
  const int* lens = (const int*)d_in[3];

  float* out_ctx = (float*)d_out;               // N*D
  float* out_attn = (float*)d_out + N_B * D_S;  // N*T

  float* p = (float*)d_ws;                                  // N*T (512 KB)
  float2* mzc = (float2*)(p + (size_t)N_B * T_S);           // N*NC (16 KB)
  float* Oc = (float*)(mzc + N_B * NC);                     // N*NC*D (2 MB)

  const dim3 grid1(NC, N_B);  // (32, 64)
  fused_kernel<<<grid1, TPB, 0, stream>>>(query, key, value, lens, p, mzc, Oc);
  const dim3 grid2(4, N_B);  // (4, 64)
  merge_kernel<<<grid2, TPB, 0, stream>>>(lens, p, mzc, Oc, out_ctx, out_attn);
}